// Round 15
// baseline (234.300 us; speedup 1.0000x reference)
//
#include <hip/hip_runtime.h>

// SelfAttention: S=4096, EMB=2048, DQ=DV=2048, causal softmax(QK^T/sqrt(DQ))V
// Round 15: un-merge S+VT (merged dispatch measured +15us from tail + L2
// competition). VT stays in the improved pipe128 form (MODE 3: wv . x^T,
// 512 blocks = one exact 2/CU fill, row-major coalesced writes).
// QK256 r10 / trimmed softmax / PVa / PVb unchanged.

using u16 = unsigned short;
typedef __bf16 bf16x8 __attribute__((ext_vector_type(8)));
typedef float  f32x4  __attribute__((ext_vector_type(4)));
typedef u16    u16x8  __attribute__((ext_vector_type(8)));

__device__ __forceinline__ u16 f2b(float f) {
  union { float f; unsigned u; } x; x.f = f;
  unsigned r = x.u + 0x7fffu + ((x.u >> 16) & 1u);  // RNE
  return (u16)(r >> 16);
}
__device__ __forceinline__ float b2f(u16 h) {
  union { unsigned u; float f; } x; x.u = ((unsigned)h) << 16;
  return x.f;
}

#define GLL16(src, dst)                                                        \
  __builtin_amdgcn_global_load_lds(                                            \
      (const __attribute__((address_space(1))) void*)(src),                    \
      (__attribute__((address_space(3))) void*)(dst), 16, 0, 0)

#define MFMA_BF16(a, b, c) __builtin_amdgcn_mfma_f32_16x16x32_bf16(a, b, c, 0, 0, 0)

// One fused cast: regions are block-aligned (2048 elems/block).
__global__ __launch_bounds__(256)
void cast_all(const float* __restrict__ x, const float* __restrict__ wq,
              const float* __restrict__ wk, const float* __restrict__ wv,
              u16* __restrict__ dst) {
  const int b = blockIdx.x;  // 10240 blocks
  const float* src;
  size_t off;
  if (b < 4096)      { src = x;  off = (size_t)b * 2048; }
  else if (b < 6144) { src = wq; off = (size_t)(b - 4096) * 2048; }
  else if (b < 8192) { src = wk; off = (size_t)(b - 6144) * 2048; }
  else               { src = wv; off = (size_t)(b - 8192) * 2048; }
  const size_t e = off + (size_t)threadIdx.x * 8;
  float4 a = *(const float4*)(src + e);
  float4 c = *(const float4*)(src + e + 4);
  u16x8 o;
  o[0] = f2b(a.x); o[1] = f2b(a.y); o[2] = f2b(a.z); o[3] = f2b(a.w);
  o[4] = f2b(c.x); o[5] = f2b(c.y); o[6] = f2b(c.z); o[7] = f2b(c.w);
  *(u16x8*)(dst + (size_t)b * 2048 + (size_t)threadIdx.x * 8) = o;
}

// ---------------------------------------------------------------------------
// QK: [Q|K] = x(4096x2048) . Wqk^T(4096x2048). 256x256 tile, BK=64, 8 waves
// 2Mx4N, grid 256 = 1/CU exact, 128KB LDS. Round-10 schedule (phase-ahead
// reads, counted lgkm, vmcnt(8)/tile, post-barrier cross-tile pre-reads).
// ---------------------------------------------------------------------------
__global__ __launch_bounds__(512)
void gemm_qk256(const u16* __restrict__ A, const u16* __restrict__ W,
                u16* __restrict__ Qo, u16* __restrict__ Ko) {
  extern __shared__ char lds[];
  constexpr int NT = 32;  // 2048/64
  const int bn = blockIdx.x, bm = blockIdx.y;
  const int tid = threadIdx.x;
  const int w = tid >> 6, lane = tid & 63;
  const int wr = w >> 2, wc = w & 3;        // 2M x 4N
  const int l15 = lane & 15, l4 = lane >> 4;
  const int rs = lane >> 3;
  const int csw = ((lane & 7) ^ rs) << 3;
  const int m0 = bm * 256, n0 = bn * 256;

  const u16* gA = A + (size_t)(m0 + w * 8 + rs) * 2048 + csw;
  const u16* gB = W + (size_t)(n0 + w * 8 + rs) * 2048 + csw;
  char* lw = lds + w * 1024;
  const u16* sm = (const u16*)lds;

  auto stA = [&](int p, int u, int tt) {
    GLL16(gA + (size_t)(u * 64) * 2048 + tt * 64, lw + p * 65536 + u * 8192);
  };
  auto stB = [&](int p, int u, int tt) {
    GLL16(gB + (size_t)(u * 64) * 2048 + tt * 64,
          lw + p * 65536 + 32768 + u * 8192);
  };
  const int swz = (l15 & 7) << 3;
  auto rdA = [&](int p, int m, int kk) -> bf16x8 {
    int u = wr * 2 + (m >> 2);
    int r64 = (m & 3) * 16 + l15;
    int e = p * 32768 + u * 4096 + ((r64 * 64 + kk * 32 + l4 * 8) ^ swz);
    return *(const bf16x8*)&sm[e];
  };
  auto rdB = [&](int p, int n, int kk) -> bf16x8 {
    int e = p * 32768 + 16384 + wc * 4096 +
            (((n * 16 + l15) * 64 + kk * 32 + l4 * 8) ^ swz);
    return *(const bf16x8*)&sm[e];
  };

  f32x4 acc[8][4] = {};
  bf16x8 a0[4][2], a1[4][2], b0[2][2], b1[2][2];

  // prologue
  stA(0,0,0); stA(0,1,0); stA(0,2,0); stA(0,3,0);
  stB(0,0,0); stB(0,1,0); stB(0,2,0); stB(0,3,0);
  stA(1,0,1); stA(1,1,1); stA(1,2,1); stA(1,3,1);
  stB(1,0,1); stB(1,1,1); stB(1,2,1); stB(1,3,1);
  asm volatile("s_waitcnt vmcnt(8)" ::: "memory");
  __builtin_amdgcn_sched_barrier(0);
  __builtin_amdgcn_s_barrier();
  // pre-read tile0 (safe: all waves past barrier => all tile0 stages landed)
#pragma unroll
  for (int m = 0; m < 4; ++m) { a0[m][0] = rdA(0,m,0); a0[m][1] = rdA(0,m,1); }
#pragma unroll
  for (int n = 0; n < 2; ++n) { b0[n][0] = rdB(0,n,0); b0[n][1] = rdB(0,n,1); }

  for (int t = 0; t < NT; ++t) {
    const int p = t & 1;
    const bool pre = (t + 2 < NT);
    // ---- ph0: read b1(4)+a1_0(2) | lgkm(6) | q00 ----
    b1[0][0] = rdB(p,2,0); b1[0][1] = rdB(p,2,1);
    b1[1][0] = rdB(p,3,0); b1[1][1] = rdB(p,3,1);
    a1[0][0] = rdA(p,4,0); a1[0][1] = rdA(p,4,1);
    asm volatile("s_waitcnt lgkmcnt(6)" ::: "memory");
    __builtin_amdgcn_sched_barrier(0);
    __builtin_amdgcn_s_setprio(1);
#pragma unroll
    for (int m = 0; m < 4; ++m)
#pragma unroll
      for (int n = 0; n < 2; ++n)
#pragma unroll
        for (int kk = 0; kk < 2; ++kk)
          acc[m][n] = MFMA_BF16(a0[m][kk], b0[n][kk], acc[m][n]);
    __builtin_amdgcn_s_setprio(0);
    __builtin_amdgcn_s_barrier();
    // ---- ph1: stage A0,A2(t+2) | read a1_123(6) | lgkm(6) | q01 ----
    if (pre) { stA(p, 0, t + 2); stA(p, 2, t + 2); }
    a1[1][0] = rdA(p,5,0); a1[1][1] = rdA(p,5,1);
    a1[2][0] = rdA(p,6,0); a1[2][1] = rdA(p,6,1);
    a1[3][0] = rdA(p,7,0); a1[3][1] = rdA(p,7,1);
    asm volatile("s_waitcnt lgkmcnt(6)" ::: "memory");
    __builtin_amdgcn_sched_barrier(0);
    __builtin_amdgcn_s_setprio(1);
#pragma unroll
    for (int m = 0; m < 4; ++m)
#pragma unroll
      for (int n = 0; n < 2; ++n)
#pragma unroll
        for (int kk = 0; kk < 2; ++kk)
          acc[m][n + 2] = MFMA_BF16(a0[m][kk], b1[n][kk], acc[m][n + 2]);
    __builtin_amdgcn_s_setprio(0);
    __builtin_amdgcn_s_barrier();
    // ---- ph2: stage B0-3(t+2) | lgkm(0) | q10 ----
    if (pre) { stB(p, 0, t + 2); stB(p, 1, t + 2); stB(p, 2, t + 2); stB(p, 3, t + 2); }
    asm volatile("s_waitcnt lgkmcnt(0)" ::: "memory");
    __builtin_amdgcn_sched_barrier(0);
    __builtin_amdgcn_s_setprio(1);
#pragma unroll
    for (int m = 0; m < 4; ++m)
#pragma unroll
      for (int n = 0; n < 2; ++n)
#pragma unroll
        for (int kk = 0; kk < 2; ++kk)
          acc[m + 4][n] = MFMA_BF16(a1[m][kk], b0[n][kk], acc[m + 4][n]);
    __builtin_amdgcn_s_setprio(0);
    __builtin_amdgcn_s_barrier();
    // ---- ph3: stage A1,A3(t+2) | q11 | vmcnt | bar | pre-read t+1 ----
    if (pre) { stA(p, 1, t + 2); stA(p, 3, t + 2); }
    __builtin_amdgcn_s_setprio(1);
#pragma unroll
    for (int m = 0; m < 4; ++m)
#pragma unroll
      for (int n = 0; n < 2; ++n)
#pragma unroll
        for (int kk = 0; kk < 2; ++kk)
          acc[m + 4][n + 2] = MFMA_BF16(a1[m][kk], b1[n][kk], acc[m + 4][n + 2]);
    __builtin_amdgcn_s_setprio(0);
    if (pre)             { asm volatile("s_waitcnt vmcnt(8)" ::: "memory"); }
    else if (t + 1 < NT) { asm volatile("s_waitcnt vmcnt(0)" ::: "memory"); }
    __builtin_amdgcn_sched_barrier(0);
    __builtin_amdgcn_s_barrier();
    if (t + 1 < NT) {
      const int pn = p ^ 1;
#pragma unroll
      for (int m = 0; m < 4; ++m) { a0[m][0] = rdA(pn,m,0); a0[m][1] = rdA(pn,m,1); }
#pragma unroll
      for (int n = 0; n < 2; ++n) { b0[n][0] = rdB(pn,n,0); b0[n][1] = rdB(pn,n,1); }
    }
  }

  const int row0 = m0 + wr * 128 + l4 * 4;
  if (bn < 8) {
    const int cg0 = bn * 256 + wc * 64 + l15;
#pragma unroll
    for (int m = 0; m < 8; ++m)
#pragma unroll
      for (int n = 0; n < 4; ++n)
#pragma unroll
        for (int j = 0; j < 4; ++j)
          Qo[(size_t)(row0 + m * 16 + j) * 2048 + cg0 + n * 16] = f2b(acc[m][n][j]);
  } else {
    const int cg0 = bn * 256 - 2048 + wc * 64 + l15;
#pragma unroll
    for (int m = 0; m < 8; ++m)
#pragma unroll
      for (int n = 0; n < 4; ++n)
#pragma unroll
        for (int j = 0; j < 4; ++j)
          Ko[(size_t)(row0 + m * 16 + j) * 2048 + cg0 + n * 16] = f2b(acc[m][n][j]);
  }
}

// ---------------------------------------------------------------------------
// pipe128: read-ahead pipeline at 128x128 tile, 4 waves (2Mx2N), BK=64,
// 64KB LDS double-buffered (2 blocks/CU), advancing stage pointers.
// MODE 0: S = alpha * Q . K^T (bf16 out ldc 4096, compact triangular 528)
// MODE 3: VT = wv . x^T       (bf16 out ldc 4096, 512 blocks = 1 exact fill,
//                              row-major coalesced writes)
// MODE 1: PVa — bm 16..31, K-tiles [0,32) uniform, f32 pure write (256 blocks)
// MODE 2: PVb — 512 blocks heavy-first: even groups = bm>=16 K-tail
//         (accumulate into PVa output); odd groups = bm<16 full-K pure write.
// ---------------------------------------------------------------------------
template<int MODE>
__global__ __launch_bounds__(256)
void pipe128(const u16* __restrict__ A, const u16* __restrict__ B,
             void* __restrict__ C, float alpha) {
  extern __shared__ char lds[];
  constexpr int LDA = (MODE == 1 || MODE == 2) ? 4096 : 2048;
  constexpr int LDB = (MODE == 1 || MODE == 2) ? 4096 : 2048;

  int bm, bn, kt0 = 0;
  bool accum = false;
  if (MODE == 0) {
    const int b = blockIdx.x;  // 528 causal tiles, bn <= bm
    int r = (int)((sqrtf(8.f * (float)b + 1.f) - 1.f) * 0.5f);
    while ((r + 1) * (r + 2) / 2 <= b) ++r;
    while (r * (r + 1) / 2 > b) --r;
    bm = r; bn = b - r * (r + 1) / 2;
  } else if (MODE == 3) {
    bm = blockIdx.x >> 5; bn = blockIdx.x & 31;  // 16 x 32 = 512
  } else if (MODE == 1) {
    bm = 16 + (blockIdx.x >> 4); bn = blockIdx.x & 15;
  } else {
    const int g = blockIdx.x >> 4;  // 32 groups, NT descending
    bn = blockIdx.x & 15;
    if ((g & 1) == 0) { bm = 31 - (g >> 1); kt0 = 32; accum = true; }
    else              { bm = 15 - (g >> 1); }
  }
  const int NT = (MODE == 2) ? (2 * (bm + 1) - kt0) : 32;

  const int tid = threadIdx.x;
  const int w = tid >> 6, lane = tid & 63;
  const int wr = w >> 1, wc = w & 1;
  const int l15 = lane & 15, l4 = lane >> 4;
  const int rs = lane >> 3;
  const int csw = ((lane & 7) ^ rs) << 3;
  const int m0 = bm * 128, n0 = bn * 128;

  const u16* gA = A + (size_t)(m0 + w * 8 + rs) * LDA + csw + (size_t)kt0 * 64;
  const u16* gB = B + (size_t)(n0 + w * 8 + rs) * LDB + csw + (size_t)kt0 * 64;
  const u16* gA0 = gA;
  const u16* gA1 = gA + (size_t)32 * LDA;
  const u16* gA2 = gA + (size_t)64 * LDA;
  const u16* gA3 = gA + (size_t)96 * LDA;
  const u16* gB0 = gB;
  const u16* gB1 = gB + (size_t)32 * LDB;
  const u16* gB2 = gB + (size_t)64 * LDB;
  const u16* gB3 = gB + (size_t)96 * LDB;
  char* lw = lds + w * 1024;
  const u16* sm = (const u16*)lds;
#define PDSTA(P, U) (lw + (P) * 32768 + (U) * 4096)
#define PDSTB(P, U) (lw + (P) * 32768 + 16384 + (U) * 4096)

  const int swz = (l15 & 7) << 3;
  auto rdA = [&](int p, int m, int kk) -> bf16x8 {
    int e = p * 16384 + wr * 4096 + (((m * 16 + l15) * 64 + kk * 32 + l4 * 8) ^ swz);
    return *(const bf16x8*)&sm[e];
  };
  auto rdB = [&](int p, int n, int kk) -> bf16x8 {
    int e = p * 16384 + 8192 + wc * 4096 +
            (((n * 16 + l15) * 64 + kk * 32 + l4 * 8) ^ swz);
    return *(const bf16x8*)&sm[e];
  };

  f32x4 acc[4][4] = {};
  bf16x8 aE[4][2], aO[4][2], b01E[2][2], b01O[2][2], b23E[2][2], b23O[2][2];

  GLL16(gA0, PDSTA(0,0)); GLL16(gA1, PDSTA(0,1));
  GLL16(gA2, PDSTA(0,2)); GLL16(gA3, PDSTA(0,3));
  GLL16(gB0, PDSTB(0,0)); GLL16(gB1, PDSTB(0,1));
  GLL16(gB2, PDSTB(0,2)); GLL16(gB3, PDSTB(0,3));
  GLL16(gA0 + 64, PDSTA(1,0)); GLL16(gA1 + 64, PDSTA(1,1));
  GLL16(gA2 + 64, PDSTA(1,2)); GLL16(gA3 + 64, PDSTA(1,3));
  GLL16(gB0 + 64, PDSTB(1,0)); GLL16(gB1 + 64, PDSTB(1,1));
  GLL16(gB2 + 64, PDSTB(1,2)); GLL16(gB3 + 64, PDSTB(1,3));
  gA0 += 128; gA1 += 128; gA2 += 128; gA3 += 128;
  gB0 += 128; gB1 += 128; gB2 += 128; gB3 += 128;
  asm volatile("s_waitcnt vmcnt(8)" ::: "memory");
  __builtin_amdgcn_sched_barrier(0);
  __builtin_amdgcn_s_barrier();
#pragma unroll
  for (int m = 0; m < 4; ++m) { aE[m][0] = rdA(0,m,0); aE[m][1] = rdA(0,m,1); }
#pragma unroll
  for (int n = 0; n < 2; ++n) { b01E[n][0] = rdB(0,n,0); b01E[n][1] = rdB(0,n,1); }
  asm volatile("s_waitcnt lgkmcnt(0)" ::: "memory");
  __builtin_amdgcn_sched_barrier(0);
  __builtin_amdgcn_s_barrier();

  for (int i = 0; i < (NT >> 1); ++i) {
    const int te = 2 * i, to = 2 * i + 1;
    // ---- tile te (buf0) ph0 ----
    if (te + 2 < NT) { GLL16(gA0, PDSTA(0,0)); GLL16(gA1, PDSTA(0,1));
                       GLL16(gA2, PDSTA(0,2)); GLL16(gA3, PDSTA(0,3)); }
#pragma unroll
    for (int n = 0; n < 2; ++n) { b23E[n][0] = rdB(0,n+2,0); b23E[n][1] = rdB(0,n+2,1); }
    __builtin_amdgcn_s_barrier();
    __builtin_amdgcn_s_setprio(1);
#pragma unroll
    for (int m = 0; m < 4; ++m)
#pragma unroll
      for (int n = 0; n < 2; ++n)
#pragma unroll
        for (int kk = 0; kk < 2; ++kk)
          acc[m][n] = MFMA_BF16(aE[m][kk], b01E[n][kk], acc[m][n]);
    __builtin_amdgcn_s_setprio(0);
    asm volatile("s_waitcnt lgkmcnt(0)" ::: "memory");
    __builtin_amdgcn_sched_barrier(0);
    __builtin_amdgcn_s_barrier();
    // ---- tile te ph1 ----
    if (te + 2 < NT) {
      GLL16(gB0, PDSTB(0,0)); GLL16(gB1, PDSTB(0,1));
      GLL16(gB2, PDSTB(0,2)); GLL16(gB3, PDSTB(0,3));
      asm volatile("s_waitcnt vmcnt(8)" ::: "memory");
    } else {
      asm volatile("s_waitcnt vmcnt(0)" ::: "memory");
    }
    __builtin_amdgcn_sched_barrier(0);
    __builtin_amdgcn_s_barrier();
#pragma unroll
    for (int m = 0; m < 4; ++m) { aO[m][0] = rdA(1,m,0); aO[m][1] = rdA(1,m,1); }
#pragma unroll
    for (int n = 0; n < 2; ++n) { b01O[n][0] = rdB(1,n,0); b01O[n][1] = rdB(1,n,1); }
    __builtin_amdgcn_s_setprio(1);
#pragma unroll
    for (int m = 0; m < 4; ++m)
#pragma unroll
      for (int n = 0; n < 2; ++n)
#pragma unroll
        for (int kk = 0; kk < 2; ++kk)
          acc[m][n+2] = MFMA_BF16(aE[m][kk], b23E[n][kk], acc[m][n+2]);
    __builtin_amdgcn_s_setprio(0);
    asm volatile("s_waitcnt lgkmcnt(0)" ::: "memory");
    __builtin_amdgcn_sched_barrier(0);
    __builtin_amdgcn_s_barrier();
    // ---- tile to (buf1) ph0 ----
    if (to + 2 < NT) { GLL16(gA0 + 64, PDSTA(1,0)); GLL16(gA1 + 64, PDSTA(1,1));
                       GLL16(gA2 + 64, PDSTA(1,2)); GLL16(gA3 + 64, PDSTA(1,3)); }
#pragma unroll
    for (int n = 0; n < 2; ++n) { b23O[n][0] = rdB(1,n+2,0); b23O[n][1] = rdB(1,n+2,1); }
    __builtin_amdgcn_s_barrier();
    __builtin_amdgcn_s_setprio(1);
#pragma unroll
    for (int m = 0; m < 4; ++m)
#pragma unroll
      for (int n = 0; n < 2; ++n)
#pragma unroll
        for (int kk = 0; kk < 2; ++kk)
          acc[m][n] = MFMA_BF16(aO[m][kk], b01O[n][kk], acc[m][n]);
    __builtin_amdgcn_s_setprio(0);
    asm volatile("s_waitcnt lgkmcnt(0)" ::: "memory");
    __builtin_amdgcn_sched_barrier(0);
    __builtin_amdgcn_s_barrier();
    // ---- tile to ph1 ----
    if (to + 2 < NT) {
      GLL16(gB0 + 64, PDSTB(1,0)); GLL16(gB1 + 64, PDSTB(1,1));
      GLL16(gB2 + 64, PDSTB(1,2)); GLL16(gB3 + 64, PDSTB(1,3));
      asm volatile("s_waitcnt vmcnt(8)" ::: "memory");
    } else if (to + 1 < NT) {
      asm volatile("s_waitcnt vmcnt(0)" ::: "memory");
    }
    __builtin_amdgcn_sched_barrier(0);
    __builtin_amdgcn_s_barrier();
    if (to + 1 < NT) {
#pragma unroll
      for (int m = 0; m < 4; ++m) { aE[m][0] = rdA(0,m,0); aE[m][1] = rdA(0,m,1); }
#pragma unroll
      for (int n = 0; n < 2; ++n) { b01E[n][0] = rdB(0,n,0); b01E[n][1] = rdB(0,n,1); }
    }
    __builtin_amdgcn_s_setprio(1);
#pragma unroll
    for (int m = 0; m < 4; ++m)
#pragma unroll
      for (int n = 0; n < 2; ++n)
#pragma unroll
        for (int kk = 0; kk < 2; ++kk)
          acc[m][n+2] = MFMA_BF16(aO[m][kk], b23O[n][kk], acc[m][n+2]);
    __builtin_amdgcn_s_setprio(0);
    asm volatile("s_waitcnt lgkmcnt(0)" ::: "memory");
    __builtin_amdgcn_sched_barrier(0);
    __builtin_amdgcn_s_barrier();
    gA0 += 128; gA1 += 128; gA2 += 128; gA3 += 128;
    gB0 += 128; gB1 += 128; gB2 += 128; gB3 += 128;
  }
#undef PDSTA
#undef PDSTB

  const int row0 = m0 + wr * 64 + l4 * 4;
  const int col0 = n0 + wc * 64 + l15;
  if (MODE == 0 || MODE == 3) {
    u16* Co = (u16*)C;
#pragma unroll
    for (int m = 0; m < 4; ++m)
#pragma unroll
      for (int n = 0; n < 4; ++n)
#pragma unroll
        for (int j = 0; j < 4; ++j)
          Co[(size_t)(row0 + m * 16 + j) * 4096 + col0 + n * 16] =
              f2b(acc[m][n][j] * alpha);
  } else {
    float* Co = (float*)C;
    if (MODE == 2 && accum) {
#pragma unroll
      for (int m = 0; m < 4; ++m)
#pragma unroll
        for (int n = 0; n < 4; ++n)
#pragma unroll
          for (int j = 0; j < 4; ++j)
            Co[(size_t)(row0 + m * 16 + j) * 2048 + col0 + n * 16] += acc[m][n][j];
    } else {
#pragma unroll
      for (int m = 0; m < 4; ++m)
#pragma unroll
        for (int n = 0; n < 4; ++n)
#pragma unroll
          for (int j = 0; j < 4; ++j)
            Co[(size_t)(row0 + m * 16 + j) * 2048 + col0 + n * 16] = acc[m][n][j];
    }
  }
}

// In-place causal row softmax over bf16 [4096][4096]; causal-trimmed:
// row i touches only cols < L = (floor(i/128)+1)*128. Cols in (i, L) get
// zeros (read by K-clamped PV); cols >= L are never read downstream.
__global__ __launch_bounds__(256)
void softmax_causal(u16* __restrict__ S) {
  const int i = blockIdx.x;
  const int t = threadIdx.x;
  u16* row = S + (size_t)i * 4096;
  const int L = ((i >> 7) + 1) << 7;
  const bool act = (t * 16) < L;

  u16x8 r0 = {}, r1 = {};
  if (act) {
    r0 = *(const u16x8*)(row + t * 16);
    r1 = *(const u16x8*)(row + t * 16 + 8);
  }

  float v[16];
  float mx = -__builtin_inff();
#pragma unroll
  for (int c = 0; c < 16; ++c) {
    int j = t * 16 + c;
    float x = b2f(c < 8 ? r0[c] : r1[c - 8]);
    v[c] = (j <= i) ? x : -__builtin_inff();
    mx = fmaxf(mx, v[c]);
  }
#pragma unroll
  for (int off = 32; off >= 1; off >>= 1) mx = fmaxf(mx, __shfl_xor(mx, off));
  __shared__ float red[8];
  if ((t & 63) == 0) red[t >> 6] = mx;
  __syncthreads();
  mx = fmaxf(fmaxf(red[0], red[1]), fmaxf(red[2], red[3]));

  float s = 0.f;
#pragma unroll
  for (int c = 0; c < 16; ++c) {
    float e = exp2f((v[c] - mx) * 1.4426950408889634f);
    v[c] = e;
    s += e;
  }
#pragma unroll
  for (int off = 32; off >= 1; off >>= 1) s += __shfl_xor(s, off);
  if ((t & 63) == 0) red[4 + (t >> 6)] = s;
  __syncthreads();
  s = red[4] + red[5] + red[6] + red[7];
  float inv = 1.0f / s;

  if (act) {
    u16x8 o0, o1;
#pragma unroll
    for (int c = 0; c < 8; ++c) {
      o0[c] = f2b(v[c] * inv);
      o1[c] = f2b(v[c + 8] * inv);
    }
    *(u16x8*)(row + t * 16) = o0;
    *(u16x8*)(row + t * 16 + 8) = o1;
  }
}

extern "C" void kernel_launch(void* const* d_in, const int* in_sizes, int n_in,
                              void* d_out, int out_size, void* d_ws, size_t ws_size,
                              hipStream_t stream) {
  const float* x  = (const float*)d_in[0];
  const float* wq = (const float*)d_in[1];
  const float* wk = (const float*)d_in[2];
  const float* wv = (const float*)d_in[3];

  // workspace layout (bf16 elements); x|wq|wk|wv contiguous for fused cast
  u16* x_bf  = (u16*)d_ws;
  u16* wq_bf = x_bf  + (size_t)4096 * 2048;
  u16* wv_bf = wq_bf + (size_t)2 * 2048 * 2048;  // third weight slab
  u16* K_bf  = wq_bf + (size_t)3 * 2048 * 2048;
  u16* VT_bf = K_bf  + (size_t)4096 * 2048;
  u16* S_bf  = VT_bf + (size_t)2048 * 4096;
  u16* Q_bf  = (u16*)d_out;  // Q parked in d_out; dead before PV overwrites

  const float alpha = 0.022097086912079612f;  // 1/sqrt(2048)

  cast_all<<<dim3(10240), 256, 0, stream>>>(x, wq, wk, wv, x_bf);

  // [Q|K] = x . Wqk^T : 256x256 tiles, grid 16x16 = 256 = exactly 1 block/CU
  gemm_qk256<<<dim3(16, 16), 512, 131072, stream>>>(x_bf, wq_bf, Q_bf, K_bf);
  // S = alpha * Q . K^T, compact causal grid (528 blocks, 2/CU)
  pipe128<0><<<dim3(528), 256, 65536, stream>>>(Q_bf, K_bf, S_bf, alpha);
  // VT = wv . x^T : 512 blocks = one exact 2/CU fill, row-major writes
  pipe128<3><<<dim3(512), 256, 65536, stream>>>(wv_bf, x_bf, VT_bf, 1.0f);
  // row softmax with causal mask, in place (causal-trimmed traffic)
  softmax_causal<<<dim3(4096), 256, 0, stream>>>(S_bf);
  // PVa: bm 16..31, K in [0,2048) — 256 uniform blocks, pure write
  pipe128<1><<<dim3(256), 256, 65536, stream>>>(S_bf, VT_bf, d_out, 1.0f);
  // PVb: K-tails (accumulate) + bm<16 full-K (write), heavy-first, 512 blocks
  pipe128<2><<<dim3(512), 256, 65536, stream>>>(S_bf, VT_bf, d_out, 1.0f);
}

// Round 16
// 233.114 us; speedup vs baseline: 1.0051x; 1.0051x over previous
//
#include <hip/hip_runtime.h>

// SelfAttention: S=4096, EMB=2048, DQ=DV=2048, causal softmax(QK^T/sqrt(DQ))V
// Round 16: revert to round-14 merged S+VT (measured best, 229.8us), with
// VT-first block ordering so residency fill 1 = pure VT (512 blocks, L2 set
// {wv,x}) and fill 2 = pure S (528 blocks, L2 set {Q,K}). QK256 r10 /
// trimmed softmax / PVa / PVb unchanged.

using u16 = unsigned short;
typedef __bf16 bf16x8 __attribute__((ext_vector_type(8)));
typedef float  f32x4  __attribute__((ext_vector_type(4)));
typedef u16    u16x8  __attribute__((ext_vector_type(8)));

__device__ __forceinline__ u16 f2b(float f) {
  union { float f; unsigned u; } x; x.f = f;
  unsigned r = x.u + 0x7fffu + ((x.u >> 16) & 1u);  // RNE
  return (u16)(r >> 16);
}
__device__ __forceinline__ float b2f(u16 h) {
  union { unsigned u; float f; } x; x.u = ((unsigned)h) << 16;
  return x.f;
}

#define GLL16(src, dst)                                                        \
  __builtin_amdgcn_global_load_lds(                                            \
      (const __attribute__((address_space(1))) void*)(src),                    \
      (__attribute__((address_space(3))) void*)(dst), 16, 0, 0)

#define MFMA_BF16(a, b, c) __builtin_amdgcn_mfma_f32_16x16x32_bf16(a, b, c, 0, 0, 0)

// One fused cast: regions are block-aligned (2048 elems/block).
__global__ __launch_bounds__(256)
void cast_all(const float* __restrict__ x, const float* __restrict__ wq,
              const float* __restrict__ wk, const float* __restrict__ wv,
              u16* __restrict__ dst) {
  const int b = blockIdx.x;  // 10240 blocks
  const float* src;
  size_t off;
  if (b < 4096)      { src = x;  off = (size_t)b * 2048; }
  else if (b < 6144) { src = wq; off = (size_t)(b - 4096) * 2048; }
  else if (b < 8192) { src = wk; off = (size_t)(b - 6144) * 2048; }
  else               { src = wv; off = (size_t)(b - 8192) * 2048; }
  const size_t e = off + (size_t)threadIdx.x * 8;
  float4 a = *(const float4*)(src + e);
  float4 c = *(const float4*)(src + e + 4);
  u16x8 o;
  o[0] = f2b(a.x); o[1] = f2b(a.y); o[2] = f2b(a.z); o[3] = f2b(a.w);
  o[4] = f2b(c.x); o[5] = f2b(c.y); o[6] = f2b(c.z); o[7] = f2b(c.w);
  *(u16x8*)(dst + (size_t)b * 2048 + (size_t)threadIdx.x * 8) = o;
}

// ---------------------------------------------------------------------------
// QK: [Q|K] = x(4096x2048) . Wqk^T(4096x2048). 256x256 tile, BK=64, 8 waves
// 2Mx4N, grid 256 = 1/CU exact, 128KB LDS. Round-10 schedule (phase-ahead
// reads, counted lgkm, vmcnt(8)/tile, post-barrier cross-tile pre-reads).
// ---------------------------------------------------------------------------
__global__ __launch_bounds__(512)
void gemm_qk256(const u16* __restrict__ A, const u16* __restrict__ W,
                u16* __restrict__ Qo, u16* __restrict__ Ko) {
  extern __shared__ char lds[];
  constexpr int NT = 32;  // 2048/64
  const int bn = blockIdx.x, bm = blockIdx.y;
  const int tid = threadIdx.x;
  const int w = tid >> 6, lane = tid & 63;
  const int wr = w >> 2, wc = w & 3;        // 2M x 4N
  const int l15 = lane & 15, l4 = lane >> 4;
  const int rs = lane >> 3;
  const int csw = ((lane & 7) ^ rs) << 3;
  const int m0 = bm * 256, n0 = bn * 256;

  const u16* gA = A + (size_t)(m0 + w * 8 + rs) * 2048 + csw;
  const u16* gB = W + (size_t)(n0 + w * 8 + rs) * 2048 + csw;
  char* lw = lds + w * 1024;
  const u16* sm = (const u16*)lds;

  auto stA = [&](int p, int u, int tt) {
    GLL16(gA + (size_t)(u * 64) * 2048 + tt * 64, lw + p * 65536 + u * 8192);
  };
  auto stB = [&](int p, int u, int tt) {
    GLL16(gB + (size_t)(u * 64) * 2048 + tt * 64,
          lw + p * 65536 + 32768 + u * 8192);
  };
  const int swz = (l15 & 7) << 3;
  auto rdA = [&](int p, int m, int kk) -> bf16x8 {
    int u = wr * 2 + (m >> 2);
    int r64 = (m & 3) * 16 + l15;
    int e = p * 32768 + u * 4096 + ((r64 * 64 + kk * 32 + l4 * 8) ^ swz);
    return *(const bf16x8*)&sm[e];
  };
  auto rdB = [&](int p, int n, int kk) -> bf16x8 {
    int e = p * 32768 + 16384 + wc * 4096 +
            (((n * 16 + l15) * 64 + kk * 32 + l4 * 8) ^ swz);
    return *(const bf16x8*)&sm[e];
  };

  f32x4 acc[8][4] = {};
  bf16x8 a0[4][2], a1[4][2], b0[2][2], b1[2][2];

  // prologue
  stA(0,0,0); stA(0,1,0); stA(0,2,0); stA(0,3,0);
  stB(0,0,0); stB(0,1,0); stB(0,2,0); stB(0,3,0);
  stA(1,0,1); stA(1,1,1); stA(1,2,1); stA(1,3,1);
  stB(1,0,1); stB(1,1,1); stB(1,2,1); stB(1,3,1);
  asm volatile("s_waitcnt vmcnt(8)" ::: "memory");
  __builtin_amdgcn_sched_barrier(0);
  __builtin_amdgcn_s_barrier();
  // pre-read tile0 (safe: all waves past barrier => all tile0 stages landed)
#pragma unroll
  for (int m = 0; m < 4; ++m) { a0[m][0] = rdA(0,m,0); a0[m][1] = rdA(0,m,1); }
#pragma unroll
  for (int n = 0; n < 2; ++n) { b0[n][0] = rdB(0,n,0); b0[n][1] = rdB(0,n,1); }

  for (int t = 0; t < NT; ++t) {
    const int p = t & 1;
    const bool pre = (t + 2 < NT);
    // ---- ph0: read b1(4)+a1_0(2) | lgkm(6) | q00 ----
    b1[0][0] = rdB(p,2,0); b1[0][1] = rdB(p,2,1);
    b1[1][0] = rdB(p,3,0); b1[1][1] = rdB(p,3,1);
    a1[0][0] = rdA(p,4,0); a1[0][1] = rdA(p,4,1);
    asm volatile("s_waitcnt lgkmcnt(6)" ::: "memory");
    __builtin_amdgcn_sched_barrier(0);
    __builtin_amdgcn_s_setprio(1);
#pragma unroll
    for (int m = 0; m < 4; ++m)
#pragma unroll
      for (int n = 0; n < 2; ++n)
#pragma unroll
        for (int kk = 0; kk < 2; ++kk)
          acc[m][n] = MFMA_BF16(a0[m][kk], b0[n][kk], acc[m][n]);
    __builtin_amdgcn_s_setprio(0);
    __builtin_amdgcn_s_barrier();
    // ---- ph1: stage A0,A2(t+2) | read a1_123(6) | lgkm(6) | q01 ----
    if (pre) { stA(p, 0, t + 2); stA(p, 2, t + 2); }
    a1[1][0] = rdA(p,5,0); a1[1][1] = rdA(p,5,1);
    a1[2][0] = rdA(p,6,0); a1[2][1] = rdA(p,6,1);
    a1[3][0] = rdA(p,7,0); a1[3][1] = rdA(p,7,1);
    asm volatile("s_waitcnt lgkmcnt(6)" ::: "memory");
    __builtin_amdgcn_sched_barrier(0);
    __builtin_amdgcn_s_setprio(1);
#pragma unroll
    for (int m = 0; m < 4; ++m)
#pragma unroll
      for (int n = 0; n < 2; ++n)
#pragma unroll
        for (int kk = 0; kk < 2; ++kk)
          acc[m][n + 2] = MFMA_BF16(a0[m][kk], b1[n][kk], acc[m][n + 2]);
    __builtin_amdgcn_s_setprio(0);
    __builtin_amdgcn_s_barrier();
    // ---- ph2: stage B0-3(t+2) | lgkm(0) | q10 ----
    if (pre) { stB(p, 0, t + 2); stB(p, 1, t + 2); stB(p, 2, t + 2); stB(p, 3, t + 2); }
    asm volatile("s_waitcnt lgkmcnt(0)" ::: "memory");
    __builtin_amdgcn_sched_barrier(0);
    __builtin_amdgcn_s_setprio(1);
#pragma unroll
    for (int m = 0; m < 4; ++m)
#pragma unroll
      for (int n = 0; n < 2; ++n)
#pragma unroll
        for (int kk = 0; kk < 2; ++kk)
          acc[m + 4][n] = MFMA_BF16(a1[m][kk], b0[n][kk], acc[m + 4][n]);
    __builtin_amdgcn_s_setprio(0);
    __builtin_amdgcn_s_barrier();
    // ---- ph3: stage A1,A3(t+2) | q11 | vmcnt | bar | pre-read t+1 ----
    if (pre) { stA(p, 1, t + 2); stA(p, 3, t + 2); }
    __builtin_amdgcn_s_setprio(1);
#pragma unroll
    for (int m = 0; m < 4; ++m)
#pragma unroll
      for (int n = 0; n < 2; ++n)
#pragma unroll
        for (int kk = 0; kk < 2; ++kk)
          acc[m + 4][n + 2] = MFMA_BF16(a1[m][kk], b1[n][kk], acc[m + 4][n + 2]);
    __builtin_amdgcn_s_setprio(0);
    if (pre)             { asm volatile("s_waitcnt vmcnt(8)" ::: "memory"); }
    else if (t + 1 < NT) { asm volatile("s_waitcnt vmcnt(0)" ::: "memory"); }
    __builtin_amdgcn_sched_barrier(0);
    __builtin_amdgcn_s_barrier();
    if (t + 1 < NT) {
      const int pn = p ^ 1;
#pragma unroll
      for (int m = 0; m < 4; ++m) { a0[m][0] = rdA(pn,m,0); a0[m][1] = rdA(pn,m,1); }
#pragma unroll
      for (int n = 0; n < 2; ++n) { b0[n][0] = rdB(pn,n,0); b0[n][1] = rdB(pn,n,1); }
    }
  }

  const int row0 = m0 + wr * 128 + l4 * 4;
  if (bn < 8) {
    const int cg0 = bn * 256 + wc * 64 + l15;
#pragma unroll
    for (int m = 0; m < 8; ++m)
#pragma unroll
      for (int n = 0; n < 4; ++n)
#pragma unroll
        for (int j = 0; j < 4; ++j)
          Qo[(size_t)(row0 + m * 16 + j) * 2048 + cg0 + n * 16] = f2b(acc[m][n][j]);
  } else {
    const int cg0 = bn * 256 - 2048 + wc * 64 + l15;
#pragma unroll
    for (int m = 0; m < 8; ++m)
#pragma unroll
      for (int n = 0; n < 4; ++n)
#pragma unroll
        for (int j = 0; j < 4; ++j)
          Ko[(size_t)(row0 + m * 16 + j) * 2048 + cg0 + n * 16] = f2b(acc[m][n][j]);
  }
}

// ---------------------------------------------------------------------------
// pipe128: read-ahead pipeline at 128x128 tile, 4 waves (2Mx2N), BK=64,
// 64KB LDS double-buffered (2 blocks/CU), advancing stage pointers.
// MODE 0: merged VT+S dispatch (1040 blocks, VT FIRST):
//   b < 512  : VT = wv . x^T (fill 1, L2 set {wv,x}; row-major writes)
//   b >= 512 : S = alpha * Q . K^T (fill 2, L2 set {Q,K}; triangular grid)
// MODE 1: PVa — bm 16..31, K-tiles [0,32) uniform, f32 pure write (256 blocks)
// MODE 2: PVb — 512 blocks heavy-first: even groups = bm>=16 K-tail
//         (accumulate into PVa output); odd groups = bm<16 full-K pure write.
// ---------------------------------------------------------------------------
template<int MODE>
__global__ __launch_bounds__(256)
void pipe128(const u16* __restrict__ A, const u16* __restrict__ B,
             void* __restrict__ C, float alpha,
             const u16* __restrict__ A2, const u16* __restrict__ B2,
             u16* __restrict__ C2) {
  extern __shared__ char lds[];
  constexpr int LDA = (MODE == 0) ? 2048 : 4096;
  constexpr int LDB = (MODE == 0) ? 2048 : 4096;

  int bm, bn, kt0 = 0;
  bool accum = false;
  const u16* Ap = A;
  const u16* Bp = B;
  u16* Cbf = (u16*)C;       // MODE 0 output (S)
  float scale = alpha;
  if (MODE == 0) {
    int b = blockIdx.x;  // 512 VT tiles first, then 528 causal S tiles
    if (b < 512) {
      bm = b >> 5; bn = b & 31;          // VT: 16 x 32
      Ap = A2; Bp = B2; Cbf = C2; scale = 1.0f;
    } else {
      b -= 512;
      int r = (int)((sqrtf(8.f * (float)b + 1.f) - 1.f) * 0.5f);
      while ((r + 1) * (r + 2) / 2 <= b) ++r;
      while (r * (r + 1) / 2 > b) --r;
      bm = r; bn = b - r * (r + 1) / 2;
    }
  } else if (MODE == 1) {
    bm = 16 + (blockIdx.x >> 4); bn = blockIdx.x & 15;
  } else {
    const int g = blockIdx.x >> 4;  // 32 groups, NT descending
    bn = blockIdx.x & 15;
    if ((g & 1) == 0) { bm = 31 - (g >> 1); kt0 = 32; accum = true; }
    else              { bm = 15 - (g >> 1); }
  }
  const int NT = (MODE == 2) ? (2 * (bm + 1) - kt0) : 32;

  const int tid = threadIdx.x;
  const int w = tid >> 6, lane = tid & 63;
  const int wr = w >> 1, wc = w & 1;
  const int l15 = lane & 15, l4 = lane >> 4;
  const int rs = lane >> 3;
  const int csw = ((lane & 7) ^ rs) << 3;
  const int m0 = bm * 128, n0 = bn * 128;

  const u16* gA = Ap + (size_t)(m0 + w * 8 + rs) * LDA + csw + (size_t)kt0 * 64;
  const u16* gB = Bp + (size_t)(n0 + w * 8 + rs) * LDB + csw + (size_t)kt0 * 64;
  const u16* gA0 = gA;
  const u16* gA1 = gA + (size_t)32 * LDA;
  const u16* gA2 = gA + (size_t)64 * LDA;
  const u16* gA3 = gA + (size_t)96 * LDA;
  const u16* gB0 = gB;
  const u16* gB1 = gB + (size_t)32 * LDB;
  const u16* gB2 = gB + (size_t)64 * LDB;
  const u16* gB3 = gB + (size_t)96 * LDB;
  char* lw = lds + w * 1024;
  const u16* sm = (const u16*)lds;
#define PDSTA(P, U) (lw + (P) * 32768 + (U) * 4096)
#define PDSTB(P, U) (lw + (P) * 32768 + 16384 + (U) * 4096)

  const int swz = (l15 & 7) << 3;
  auto rdA = [&](int p, int m, int kk) -> bf16x8 {
    int e = p * 16384 + wr * 4096 + (((m * 16 + l15) * 64 + kk * 32 + l4 * 8) ^ swz);
    return *(const bf16x8*)&sm[e];
  };
  auto rdB = [&](int p, int n, int kk) -> bf16x8 {
    int e = p * 16384 + 8192 + wc * 4096 +
            (((n * 16 + l15) * 64 + kk * 32 + l4 * 8) ^ swz);
    return *(const bf16x8*)&sm[e];
  };

  f32x4 acc[4][4] = {};
  bf16x8 aE[4][2], aO[4][2], b01E[2][2], b01O[2][2], b23E[2][2], b23O[2][2];

  GLL16(gA0, PDSTA(0,0)); GLL16(gA1, PDSTA(0,1));
  GLL16(gA2, PDSTA(0,2)); GLL16(gA3, PDSTA(0,3));
  GLL16(gB0, PDSTB(0,0)); GLL16(gB1, PDSTB(0,1));
  GLL16(gB2, PDSTB(0,2)); GLL16(gB3, PDSTB(0,3));
  GLL16(gA0 + 64, PDSTA(1,0)); GLL16(gA1 + 64, PDSTA(1,1));
  GLL16(gA2 + 64, PDSTA(1,2)); GLL16(gA3 + 64, PDSTA(1,3));
  GLL16(gB0 + 64, PDSTB(1,0)); GLL16(gB1 + 64, PDSTB(1,1));
  GLL16(gB2 + 64, PDSTB(1,2)); GLL16(gB3 + 64, PDSTB(1,3));
  gA0 += 128; gA1 += 128; gA2 += 128; gA3 += 128;
  gB0 += 128; gB1 += 128; gB2 += 128; gB3 += 128;
  asm volatile("s_waitcnt vmcnt(8)" ::: "memory");
  __builtin_amdgcn_sched_barrier(0);
  __builtin_amdgcn_s_barrier();
#pragma unroll
  for (int m = 0; m < 4; ++m) { aE[m][0] = rdA(0,m,0); aE[m][1] = rdA(0,m,1); }
#pragma unroll
  for (int n = 0; n < 2; ++n) { b01E[n][0] = rdB(0,n,0); b01E[n][1] = rdB(0,n,1); }
  asm volatile("s_waitcnt lgkmcnt(0)" ::: "memory");
  __builtin_amdgcn_sched_barrier(0);
  __builtin_amdgcn_s_barrier();

  for (int i = 0; i < (NT >> 1); ++i) {
    const int te = 2 * i, to = 2 * i + 1;
    // ---- tile te (buf0) ph0 ----
    if (te + 2 < NT) { GLL16(gA0, PDSTA(0,0)); GLL16(gA1, PDSTA(0,1));
                       GLL16(gA2, PDSTA(0,2)); GLL16(gA3, PDSTA(0,3)); }
#pragma unroll
    for (int n = 0; n < 2; ++n) { b23E[n][0] = rdB(0,n+2,0); b23E[n][1] = rdB(0,n+2,1); }
    __builtin_amdgcn_s_barrier();
    __builtin_amdgcn_s_setprio(1);
#pragma unroll
    for (int m = 0; m < 4; ++m)
#pragma unroll
      for (int n = 0; n < 2; ++n)
#pragma unroll
        for (int kk = 0; kk < 2; ++kk)
          acc[m][n] = MFMA_BF16(aE[m][kk], b01E[n][kk], acc[m][n]);
    __builtin_amdgcn_s_setprio(0);
    asm volatile("s_waitcnt lgkmcnt(0)" ::: "memory");
    __builtin_amdgcn_sched_barrier(0);
    __builtin_amdgcn_s_barrier();
    // ---- tile te ph1 ----
    if (te + 2 < NT) {
      GLL16(gB0, PDSTB(0,0)); GLL16(gB1, PDSTB(0,1));
      GLL16(gB2, PDSTB(0,2)); GLL16(gB3, PDSTB(0,3));
      asm volatile("s_waitcnt vmcnt(8)" ::: "memory");
    } else {
      asm volatile("s_waitcnt vmcnt(0)" ::: "memory");
    }
    __builtin_amdgcn_sched_barrier(0);
    __builtin_amdgcn_s_barrier();
#pragma unroll
    for (int m = 0; m < 4; ++m) { aO[m][0] = rdA(1,m,0); aO[m][1] = rdA(1,m,1); }
#pragma unroll
    for (int n = 0; n < 2; ++n) { b01O[n][0] = rdB(1,n,0); b01O[n][1] = rdB(1,n,1); }
    __builtin_amdgcn_s_setprio(1);
#pragma unroll
    for (int m = 0; m < 4; ++m)
#pragma unroll
      for (int n = 0; n < 2; ++n)
#pragma unroll
        for (int kk = 0; kk < 2; ++kk)
          acc[m][n+2] = MFMA_BF16(aE[m][kk], b23E[n][kk], acc[m][n+2]);
    __builtin_amdgcn_s_setprio(0);
    asm volatile("s_waitcnt lgkmcnt(0)" ::: "memory");
    __builtin_amdgcn_sched_barrier(0);
    __builtin_amdgcn_s_barrier();
    // ---- tile to (buf1) ph0 ----
    if (to + 2 < NT) { GLL16(gA0 + 64, PDSTA(1,0)); GLL16(gA1 + 64, PDSTA(1,1));
                       GLL16(gA2 + 64, PDSTA(1,2)); GLL16(gA3 + 64, PDSTA(1,3)); }
#pragma unroll
    for (int n = 0; n < 2; ++n) { b23O[n][0] = rdB(1,n+2,0); b23O[n][1] = rdB(1,n+2,1); }
    __builtin_amdgcn_s_barrier();
    __builtin_amdgcn_s_setprio(1);
#pragma unroll
    for (int m = 0; m < 4; ++m)
#pragma unroll
      for (int n = 0; n < 2; ++n)
#pragma unroll
        for (int kk = 0; kk < 2; ++kk)
          acc[m][n] = MFMA_BF16(aO[m][kk], b01O[n][kk], acc[m][n]);
    __builtin_amdgcn_s_setprio(0);
    asm volatile("s_waitcnt lgkmcnt(0)" ::: "memory");
    __builtin_amdgcn_sched_barrier(0);
    __builtin_amdgcn_s_barrier();
    // ---- tile to ph1 ----
    if (to + 2 < NT) {
      GLL16(gB0 + 64, PDSTB(1,0)); GLL16(gB1 + 64, PDSTB(1,1));
      GLL16(gB2 + 64, PDSTB(1,2)); GLL16(gB3 + 64, PDSTB(1,3));
      asm volatile("s_waitcnt vmcnt(8)" ::: "memory");
    } else if (to + 1 < NT) {
      asm volatile("s_waitcnt vmcnt(0)" ::: "memory");
    }
    __builtin_amdgcn_sched_barrier(0);
    __builtin_amdgcn_s_barrier();
    if (to + 1 < NT) {
#pragma unroll
      for (int m = 0; m < 4; ++m) { aE[m][0] = rdA(0,m,0); aE[m][1] = rdA(0,m,1); }
#pragma unroll
      for (int n = 0; n < 2; ++n) { b01E[n][0] = rdB(0,n,0); b01E[n][1] = rdB(0,n,1); }
    }
    __builtin_amdgcn_s_setprio(1);
#pragma unroll
    for (int m = 0; m < 4; ++m)
#pragma unroll
      for (int n = 0; n < 2; ++n)
#pragma unroll
        for (int kk = 0; kk < 2; ++kk)
          acc[m][n+2] = MFMA_BF16(aO[m][kk], b23O[n][kk], acc[m][n+2]);
    __builtin_amdgcn_s_setprio(0);
    asm volatile("s_waitcnt lgkmcnt(0)" ::: "memory");
    __builtin_amdgcn_sched_barrier(0);
    __builtin_amdgcn_s_barrier();
    gA0 += 128; gA1 += 128; gA2 += 128; gA3 += 128;
    gB0 += 128; gB1 += 128; gB2 += 128; gB3 += 128;
  }
#undef PDSTA
#undef PDSTB

  const int row0 = m0 + wr * 64 + l4 * 4;
  const int col0 = n0 + wc * 64 + l15;
  if (MODE == 0) {
#pragma unroll
    for (int m = 0; m < 4; ++m)
#pragma unroll
      for (int n = 0; n < 4; ++n)
#pragma unroll
        for (int j = 0; j < 4; ++j)
          Cbf[(size_t)(row0 + m * 16 + j) * 4096 + col0 + n * 16] =
              f2b(acc[m][n][j] * scale);
  } else {
    float* Co = (float*)C;
    if (MODE == 2 && accum) {
#pragma unroll
      for (int m = 0; m < 4; ++m)
#pragma unroll
        for (int n = 0; n < 4; ++n)
#pragma unroll
          for (int j = 0; j < 4; ++j)
            Co[(size_t)(row0 + m * 16 + j) * 2048 + col0 + n * 16] += acc[m][n][j];
    } else {
#pragma unroll
      for (int m = 0; m < 4; ++m)
#pragma unroll
        for (int n = 0; n < 4; ++n)
#pragma unroll
          for (int j = 0; j < 4; ++j)
            Co[(size_t)(row0 + m * 16 + j) * 2048 + col0 + n * 16] = acc[m][n][j];
    }
  }
}

// In-place causal row softmax over bf16 [4096][4096]; causal-trimmed:
// row i touches only cols < L = (floor(i/128)+1)*128. Cols in (i, L) get
// zeros (read by K-clamped PV); cols >= L are never read downstream.
__global__ __launch_bounds__(256)
void softmax_causal(u16* __restrict__ S) {
  const int i = blockIdx.x;
  const int t = threadIdx.x;
  u16* row = S + (size_t)i * 4096;
  const int L = ((i >> 7) + 1) << 7;
  const bool act = (t * 16) < L;

  u16x8 r0 = {}, r1 = {};
  if (act) {
    r0 = *(const u16x8*)(row + t * 16);
    r1 = *(const u16x8*)(row + t * 16 + 8);
  }

  float v[16];
  float mx = -__builtin_inff();
#pragma unroll
  for (int c = 0; c < 16; ++c) {
    int j = t * 16 + c;
    float x = b2f(c < 8 ? r0[c] : r1[c - 8]);
    v[c] = (j <= i) ? x : -__builtin_inff();
    mx = fmaxf(mx, v[c]);
  }
#pragma unroll
  for (int off = 32; off >= 1; off >>= 1) mx = fmaxf(mx, __shfl_xor(mx, off));
  __shared__ float red[8];
  if ((t & 63) == 0) red[t >> 6] = mx;
  __syncthreads();
  mx = fmaxf(fmaxf(red[0], red[1]), fmaxf(red[2], red[3]));

  float s = 0.f;
#pragma unroll
  for (int c = 0; c < 16; ++c) {
    float e = exp2f((v[c] - mx) * 1.4426950408889634f);
    v[c] = e;
    s += e;
  }
#pragma unroll
  for (int off = 32; off >= 1; off >>= 1) s += __shfl_xor(s, off);
  if ((t & 63) == 0) red[4 + (t >> 6)] = s;
  __syncthreads();
  s = red[4] + red[5] + red[6] + red[7];
  float inv = 1.0f / s;

  if (act) {
    u16x8 o0, o1;
#pragma unroll
    for (int c = 0; c < 8; ++c) {
      o0[c] = f2b(v[c] * inv);
      o1[c] = f2b(v[c + 8] * inv);
    }
    *(u16x8*)(row + t * 16) = o0;
    *(u16x8*)(row + t * 16 + 8) = o1;
  }
}

extern "C" void kernel_launch(void* const* d_in, const int* in_sizes, int n_in,
                              void* d_out, int out_size, void* d_ws, size_t ws_size,
                              hipStream_t stream) {
  const float* x  = (const float*)d_in[0];
  const float* wq = (const float*)d_in[1];
  const float* wk = (const float*)d_in[2];
  const float* wv = (const float*)d_in[3];

  // workspace layout (bf16 elements); x|wq|wk|wv contiguous for fused cast
  u16* x_bf  = (u16*)d_ws;
  u16* wq_bf = x_bf  + (size_t)4096 * 2048;
  u16* wv_bf = wq_bf + (size_t)2 * 2048 * 2048;  // third weight slab
  u16* K_bf  = wq_bf + (size_t)3 * 2048 * 2048;
  u16* VT_bf = K_bf  + (size_t)4096 * 2048;
  u16* S_bf  = VT_bf + (size_t)2048 * 4096;
  u16* Q_bf  = (u16*)d_out;  // Q parked in d_out; dead before PV overwrites

  const float alpha = 0.022097086912079612f;  // 1/sqrt(2048)

  cast_all<<<dim3(10240), 256, 0, stream>>>(x, wq, wk, wv, x_bf);

  // [Q|K] = x . Wqk^T : 256x256 tiles, grid 16x16 = 256 = exactly 1 block/CU
  gemm_qk256<<<dim3(16, 16), 512, 131072, stream>>>(x_bf, wq_bf, Q_bf, K_bf);
  // Merged: VT = wv . x^T (512 blocks, fill 1) + S = alpha*Q.K^T (528, fill 2)
  pipe128<0><<<dim3(1040), 256, 65536, stream>>>(
      Q_bf, K_bf, S_bf, alpha, wv_bf, x_bf, VT_bf);
  // row softmax with causal mask, in place (causal-trimmed traffic)
  softmax_causal<<<dim3(4096), 256, 0, stream>>>(S_bf);
  // PVa: bm 16..31, K in [0,2048) — 256 uniform blocks, pure write
  pipe128<1><<<dim3(256), 256, 65536, stream>>>(
      S_bf, VT_bf, d_out, 1.0f, nullptr, nullptr, nullptr);
  // PVb: K-tails (accumulate) + bm<16 full-K (write), heavy-first, 512 blocks
  pipe128<2><<<dim3(512), 256, 65536, stream>>>(
      S_bf, VT_bf, d_out, 1.0f, nullptr, nullptr, nullptr);
}

// Round 17
// 229.259 us; speedup vs baseline: 1.0220x; 1.0168x over previous
//
#include <hip/hip_runtime.h>

// SelfAttention: S=4096, EMB=2048, DQ=DV=2048, causal softmax(QK^T/sqrt(DQ))V
// FINAL (= round-14 measured best, 229.8us): merged S+VT single dispatch
// (S-first), QK256 round-10 schedule, causal-trimmed softmax, PVa/PVb split
// with heavy-first tails. All components are the best-measured variants.

using u16 = unsigned short;
typedef __bf16 bf16x8 __attribute__((ext_vector_type(8)));
typedef float  f32x4  __attribute__((ext_vector_type(4)));
typedef u16    u16x8  __attribute__((ext_vector_type(8)));

__device__ __forceinline__ u16 f2b(float f) {
  union { float f; unsigned u; } x; x.f = f;
  unsigned r = x.u + 0x7fffu + ((x.u >> 16) & 1u);  // RNE
  return (u16)(r >> 16);
}
__device__ __forceinline__ float b2f(u16 h) {
  union { unsigned u; float f; } x; x.u = ((unsigned)h) << 16;
  return x.f;
}

#define GLL16(src, dst)                                                        \
  __builtin_amdgcn_global_load_lds(                                            \
      (const __attribute__((address_space(1))) void*)(src),                    \
      (__attribute__((address_space(3))) void*)(dst), 16, 0, 0)

#define MFMA_BF16(a, b, c) __builtin_amdgcn_mfma_f32_16x16x32_bf16(a, b, c, 0, 0, 0)

// One fused cast: regions are block-aligned (2048 elems/block).
__global__ __launch_bounds__(256)
void cast_all(const float* __restrict__ x, const float* __restrict__ wq,
              const float* __restrict__ wk, const float* __restrict__ wv,
              u16* __restrict__ dst) {
  const int b = blockIdx.x;  // 10240 blocks
  const float* src;
  size_t off;
  if (b < 4096)      { src = x;  off = (size_t)b * 2048; }
  else if (b < 6144) { src = wq; off = (size_t)(b - 4096) * 2048; }
  else if (b < 8192) { src = wk; off = (size_t)(b - 6144) * 2048; }
  else               { src = wv; off = (size_t)(b - 8192) * 2048; }
  const size_t e = off + (size_t)threadIdx.x * 8;
  float4 a = *(const float4*)(src + e);
  float4 c = *(const float4*)(src + e + 4);
  u16x8 o;
  o[0] = f2b(a.x); o[1] = f2b(a.y); o[2] = f2b(a.z); o[3] = f2b(a.w);
  o[4] = f2b(c.x); o[5] = f2b(c.y); o[6] = f2b(c.z); o[7] = f2b(c.w);
  *(u16x8*)(dst + (size_t)b * 2048 + (size_t)threadIdx.x * 8) = o;
}

// ---------------------------------------------------------------------------
// QK: [Q|K] = x(4096x2048) . Wqk^T(4096x2048). 256x256 tile, BK=64, 8 waves
// 2Mx4N, grid 256 = 1/CU exact, 128KB LDS. Round-10 schedule (phase-ahead
// reads, counted lgkm, vmcnt(8)/tile, post-barrier cross-tile pre-reads).
// ---------------------------------------------------------------------------
__global__ __launch_bounds__(512)
void gemm_qk256(const u16* __restrict__ A, const u16* __restrict__ W,
                u16* __restrict__ Qo, u16* __restrict__ Ko) {
  extern __shared__ char lds[];
  constexpr int NT = 32;  // 2048/64
  const int bn = blockIdx.x, bm = blockIdx.y;
  const int tid = threadIdx.x;
  const int w = tid >> 6, lane = tid & 63;
  const int wr = w >> 2, wc = w & 3;        // 2M x 4N
  const int l15 = lane & 15, l4 = lane >> 4;
  const int rs = lane >> 3;
  const int csw = ((lane & 7) ^ rs) << 3;
  const int m0 = bm * 256, n0 = bn * 256;

  const u16* gA = A + (size_t)(m0 + w * 8 + rs) * 2048 + csw;
  const u16* gB = W + (size_t)(n0 + w * 8 + rs) * 2048 + csw;
  char* lw = lds + w * 1024;
  const u16* sm = (const u16*)lds;

  auto stA = [&](int p, int u, int tt) {
    GLL16(gA + (size_t)(u * 64) * 2048 + tt * 64, lw + p * 65536 + u * 8192);
  };
  auto stB = [&](int p, int u, int tt) {
    GLL16(gB + (size_t)(u * 64) * 2048 + tt * 64,
          lw + p * 65536 + 32768 + u * 8192);
  };
  const int swz = (l15 & 7) << 3;
  auto rdA = [&](int p, int m, int kk) -> bf16x8 {
    int u = wr * 2 + (m >> 2);
    int r64 = (m & 3) * 16 + l15;
    int e = p * 32768 + u * 4096 + ((r64 * 64 + kk * 32 + l4 * 8) ^ swz);
    return *(const bf16x8*)&sm[e];
  };
  auto rdB = [&](int p, int n, int kk) -> bf16x8 {
    int e = p * 32768 + 16384 + wc * 4096 +
            (((n * 16 + l15) * 64 + kk * 32 + l4 * 8) ^ swz);
    return *(const bf16x8*)&sm[e];
  };

  f32x4 acc[8][4] = {};
  bf16x8 a0[4][2], a1[4][2], b0[2][2], b1[2][2];

  // prologue
  stA(0,0,0); stA(0,1,0); stA(0,2,0); stA(0,3,0);
  stB(0,0,0); stB(0,1,0); stB(0,2,0); stB(0,3,0);
  stA(1,0,1); stA(1,1,1); stA(1,2,1); stA(1,3,1);
  stB(1,0,1); stB(1,1,1); stB(1,2,1); stB(1,3,1);
  asm volatile("s_waitcnt vmcnt(8)" ::: "memory");
  __builtin_amdgcn_sched_barrier(0);
  __builtin_amdgcn_s_barrier();
  // pre-read tile0 (safe: all waves past barrier => all tile0 stages landed)
#pragma unroll
  for (int m = 0; m < 4; ++m) { a0[m][0] = rdA(0,m,0); a0[m][1] = rdA(0,m,1); }
#pragma unroll
  for (int n = 0; n < 2; ++n) { b0[n][0] = rdB(0,n,0); b0[n][1] = rdB(0,n,1); }

  for (int t = 0; t < NT; ++t) {
    const int p = t & 1;
    const bool pre = (t + 2 < NT);
    // ---- ph0: read b1(4)+a1_0(2) | lgkm(6) | q00 ----
    b1[0][0] = rdB(p,2,0); b1[0][1] = rdB(p,2,1);
    b1[1][0] = rdB(p,3,0); b1[1][1] = rdB(p,3,1);
    a1[0][0] = rdA(p,4,0); a1[0][1] = rdA(p,4,1);
    asm volatile("s_waitcnt lgkmcnt(6)" ::: "memory");
    __builtin_amdgcn_sched_barrier(0);
    __builtin_amdgcn_s_setprio(1);
#pragma unroll
    for (int m = 0; m < 4; ++m)
#pragma unroll
      for (int n = 0; n < 2; ++n)
#pragma unroll
        for (int kk = 0; kk < 2; ++kk)
          acc[m][n] = MFMA_BF16(a0[m][kk], b0[n][kk], acc[m][n]);
    __builtin_amdgcn_s_setprio(0);
    __builtin_amdgcn_s_barrier();
    // ---- ph1: stage A0,A2(t+2) | read a1_123(6) | lgkm(6) | q01 ----
    if (pre) { stA(p, 0, t + 2); stA(p, 2, t + 2); }
    a1[1][0] = rdA(p,5,0); a1[1][1] = rdA(p,5,1);
    a1[2][0] = rdA(p,6,0); a1[2][1] = rdA(p,6,1);
    a1[3][0] = rdA(p,7,0); a1[3][1] = rdA(p,7,1);
    asm volatile("s_waitcnt lgkmcnt(6)" ::: "memory");
    __builtin_amdgcn_sched_barrier(0);
    __builtin_amdgcn_s_setprio(1);
#pragma unroll
    for (int m = 0; m < 4; ++m)
#pragma unroll
      for (int n = 0; n < 2; ++n)
#pragma unroll
        for (int kk = 0; kk < 2; ++kk)
          acc[m][n + 2] = MFMA_BF16(a0[m][kk], b1[n][kk], acc[m][n + 2]);
    __builtin_amdgcn_s_setprio(0);
    __builtin_amdgcn_s_barrier();
    // ---- ph2: stage B0-3(t+2) | lgkm(0) | q10 ----
    if (pre) { stB(p, 0, t + 2); stB(p, 1, t + 2); stB(p, 2, t + 2); stB(p, 3, t + 2); }
    asm volatile("s_waitcnt lgkmcnt(0)" ::: "memory");
    __builtin_amdgcn_sched_barrier(0);
    __builtin_amdgcn_s_setprio(1);
#pragma unroll
    for (int m = 0; m < 4; ++m)
#pragma unroll
      for (int n = 0; n < 2; ++n)
#pragma unroll
        for (int kk = 0; kk < 2; ++kk)
          acc[m + 4][n] = MFMA_BF16(a1[m][kk], b0[n][kk], acc[m + 4][n]);
    __builtin_amdgcn_s_setprio(0);
    __builtin_amdgcn_s_barrier();
    // ---- ph3: stage A1,A3(t+2) | q11 | vmcnt | bar | pre-read t+1 ----
    if (pre) { stA(p, 1, t + 2); stA(p, 3, t + 2); }
    __builtin_amdgcn_s_setprio(1);
#pragma unroll
    for (int m = 0; m < 4; ++m)
#pragma unroll
      for (int n = 0; n < 2; ++n)
#pragma unroll
        for (int kk = 0; kk < 2; ++kk)
          acc[m + 4][n + 2] = MFMA_BF16(a1[m][kk], b1[n][kk], acc[m + 4][n + 2]);
    __builtin_amdgcn_s_setprio(0);
    if (pre)             { asm volatile("s_waitcnt vmcnt(8)" ::: "memory"); }
    else if (t + 1 < NT) { asm volatile("s_waitcnt vmcnt(0)" ::: "memory"); }
    __builtin_amdgcn_sched_barrier(0);
    __builtin_amdgcn_s_barrier();
    if (t + 1 < NT) {
      const int pn = p ^ 1;
#pragma unroll
      for (int m = 0; m < 4; ++m) { a0[m][0] = rdA(pn,m,0); a0[m][1] = rdA(pn,m,1); }
#pragma unroll
      for (int n = 0; n < 2; ++n) { b0[n][0] = rdB(pn,n,0); b0[n][1] = rdB(pn,n,1); }
    }
  }

  const int row0 = m0 + wr * 128 + l4 * 4;
  if (bn < 8) {
    const int cg0 = bn * 256 + wc * 64 + l15;
#pragma unroll
    for (int m = 0; m < 8; ++m)
#pragma unroll
      for (int n = 0; n < 4; ++n)
#pragma unroll
        for (int j = 0; j < 4; ++j)
          Qo[(size_t)(row0 + m * 16 + j) * 2048 + cg0 + n * 16] = f2b(acc[m][n][j]);
  } else {
    const int cg0 = bn * 256 - 2048 + wc * 64 + l15;
#pragma unroll
    for (int m = 0; m < 8; ++m)
#pragma unroll
      for (int n = 0; n < 4; ++n)
#pragma unroll
        for (int j = 0; j < 4; ++j)
          Ko[(size_t)(row0 + m * 16 + j) * 2048 + cg0 + n * 16] = f2b(acc[m][n][j]);
  }
}

// ---------------------------------------------------------------------------
// pipe128: read-ahead pipeline at 128x128 tile, 4 waves (2Mx2N), BK=64,
// 64KB LDS double-buffered (2 blocks/CU), advancing stage pointers.
// MODE 0: merged S+VT dispatch (1040 blocks):
//   b < 528  : S = alpha * Q . K^T (compact triangular causal grid)
//   b >= 528 : VT = wv . x^T (512 blocks; row-major coalesced bf16 writes)
// MODE 1: PVa — bm 16..31, K-tiles [0,32) uniform, f32 pure write (256 blocks)
// MODE 2: PVb — 512 blocks heavy-first: even groups = bm>=16 K-tail
//         (accumulate into PVa output); odd groups = bm<16 full-K pure write.
// ---------------------------------------------------------------------------
template<int MODE>
__global__ __launch_bounds__(256)
void pipe128(const u16* __restrict__ A, const u16* __restrict__ B,
             void* __restrict__ C, float alpha,
             const u16* __restrict__ A2, const u16* __restrict__ B2,
             u16* __restrict__ C2) {
  extern __shared__ char lds[];
  constexpr int LDA = (MODE == 0) ? 2048 : 4096;
  constexpr int LDB = (MODE == 0) ? 2048 : 4096;

  int bm, bn, kt0 = 0;
  bool accum = false;
  const u16* Ap = A;
  const u16* Bp = B;
  u16* Cbf = (u16*)C;       // MODE 0 output
  float scale = alpha;
  if (MODE == 0) {
    int b = blockIdx.x;  // 528 causal S tiles, then 512 VT tiles
    if (b < 528) {
      int r = (int)((sqrtf(8.f * (float)b + 1.f) - 1.f) * 0.5f);
      while ((r + 1) * (r + 2) / 2 <= b) ++r;
      while (r * (r + 1) / 2 > b) --r;
      bm = r; bn = b - r * (r + 1) / 2;
    } else {
      b -= 528;
      bm = b >> 5; bn = b & 31;
      Ap = A2; Bp = B2; Cbf = C2; scale = 1.0f;
    }
  } else if (MODE == 1) {
    bm = 16 + (blockIdx.x >> 4); bn = blockIdx.x & 15;
  } else {
    const int g = blockIdx.x >> 4;  // 32 groups, NT descending
    bn = blockIdx.x & 15;
    if ((g & 1) == 0) { bm = 31 - (g >> 1); kt0 = 32; accum = true; }
    else              { bm = 15 - (g >> 1); }
  }
  const int NT = (MODE == 0 || MODE == 1) ? 32 : (2 * (bm + 1) - kt0);

  const int tid = threadIdx.x;
  const int w = tid >> 6, lane = tid & 63;
  const int wr = w >> 1, wc = w & 1;
  const int l15 = lane & 15, l4 = lane >> 4;
  const int rs = lane >> 3;
  const int csw = ((lane & 7) ^ rs) << 3;
  const int m0 = bm * 128, n0 = bn * 128;

  const u16* gA = Ap + (size_t)(m0 + w * 8 + rs) * LDA + csw + (size_t)kt0 * 64;
  const u16* gB = Bp + (size_t)(n0 + w * 8 + rs) * LDB + csw + (size_t)kt0 * 64;
  const u16* gA0 = gA;
  const u16* gA1 = gA + (size_t)32 * LDA;
  const u16* gA2 = gA + (size_t)64 * LDA;
  const u16* gA3 = gA + (size_t)96 * LDA;
  const u16* gB0 = gB;
  const u16* gB1 = gB + (size_t)32 * LDB;
  const u16* gB2 = gB + (size_t)64 * LDB;
  const u16* gB3 = gB + (size_t)96 * LDB;
  char* lw = lds + w * 1024;
  const u16* sm = (const u16*)lds;
#define PDSTA(P, U) (lw + (P) * 32768 + (U) * 4096)
#define PDSTB(P, U) (lw + (P) * 32768 + 16384 + (U) * 4096)

  const int swz = (l15 & 7) << 3;
  auto rdA = [&](int p, int m, int kk) -> bf16x8 {
    int e = p * 16384 + wr * 4096 + (((m * 16 + l15) * 64 + kk * 32 + l4 * 8) ^ swz);
    return *(const bf16x8*)&sm[e];
  };
  auto rdB = [&](int p, int n, int kk) -> bf16x8 {
    int e = p * 16384 + 8192 + wc * 4096 +
            (((n * 16 + l15) * 64 + kk * 32 + l4 * 8) ^ swz);
    return *(const bf16x8*)&sm[e];
  };

  f32x4 acc[4][4] = {};
  bf16x8 aE[4][2], aO[4][2], b01E[2][2], b01O[2][2], b23E[2][2], b23O[2][2];

  GLL16(gA0, PDSTA(0,0)); GLL16(gA1, PDSTA(0,1));
  GLL16(gA2, PDSTA(0,2)); GLL16(gA3, PDSTA(0,3));
  GLL16(gB0, PDSTB(0,0)); GLL16(gB1, PDSTB(0,1));
  GLL16(gB2, PDSTB(0,2)); GLL16(gB3, PDSTB(0,3));
  GLL16(gA0 + 64, PDSTA(1,0)); GLL16(gA1 + 64, PDSTA(1,1));
  GLL16(gA2 + 64, PDSTA(1,2)); GLL16(gA3 + 64, PDSTA(1,3));
  GLL16(gB0 + 64, PDSTB(1,0)); GLL16(gB1 + 64, PDSTB(1,1));
  GLL16(gB2 + 64, PDSTB(1,2)); GLL16(gB3 + 64, PDSTB(1,3));
  gA0 += 128; gA1 += 128; gA2 += 128; gA3 += 128;
  gB0 += 128; gB1 += 128; gB2 += 128; gB3 += 128;
  asm volatile("s_waitcnt vmcnt(8)" ::: "memory");
  __builtin_amdgcn_sched_barrier(0);
  __builtin_amdgcn_s_barrier();
#pragma unroll
  for (int m = 0; m < 4; ++m) { aE[m][0] = rdA(0,m,0); aE[m][1] = rdA(0,m,1); }
#pragma unroll
  for (int n = 0; n < 2; ++n) { b01E[n][0] = rdB(0,n,0); b01E[n][1] = rdB(0,n,1); }
  asm volatile("s_waitcnt lgkmcnt(0)" ::: "memory");
  __builtin_amdgcn_sched_barrier(0);
  __builtin_amdgcn_s_barrier();

  for (int i = 0; i < (NT >> 1); ++i) {
    const int te = 2 * i, to = 2 * i + 1;
    // ---- tile te (buf0) ph0 ----
    if (te + 2 < NT) { GLL16(gA0, PDSTA(0,0)); GLL16(gA1, PDSTA(0,1));
                       GLL16(gA2, PDSTA(0,2)); GLL16(gA3, PDSTA(0,3)); }
#pragma unroll
    for (int n = 0; n < 2; ++n) { b23E[n][0] = rdB(0,n+2,0); b23E[n][1] = rdB(0,n+2,1); }
    __builtin_amdgcn_s_barrier();
    __builtin_amdgcn_s_setprio(1);
#pragma unroll
    for (int m = 0; m < 4; ++m)
#pragma unroll
      for (int n = 0; n < 2; ++n)
#pragma unroll
        for (int kk = 0; kk < 2; ++kk)
          acc[m][n] = MFMA_BF16(aE[m][kk], b01E[n][kk], acc[m][n]);
    __builtin_amdgcn_s_setprio(0);
    asm volatile("s_waitcnt lgkmcnt(0)" ::: "memory");
    __builtin_amdgcn_sched_barrier(0);
    __builtin_amdgcn_s_barrier();
    // ---- tile te ph1 ----
    if (te + 2 < NT) {
      GLL16(gB0, PDSTB(0,0)); GLL16(gB1, PDSTB(0,1));
      GLL16(gB2, PDSTB(0,2)); GLL16(gB3, PDSTB(0,3));
      asm volatile("s_waitcnt vmcnt(8)" ::: "memory");
    } else {
      asm volatile("s_waitcnt vmcnt(0)" ::: "memory");
    }
    __builtin_amdgcn_sched_barrier(0);
    __builtin_amdgcn_s_barrier();
#pragma unroll
    for (int m = 0; m < 4; ++m) { aO[m][0] = rdA(1,m,0); aO[m][1] = rdA(1,m,1); }
#pragma unroll
    for (int n = 0; n < 2; ++n) { b01O[n][0] = rdB(1,n,0); b01O[n][1] = rdB(1,n,1); }
    __builtin_amdgcn_s_setprio(1);
#pragma unroll
    for (int m = 0; m < 4; ++m)
#pragma unroll
      for (int n = 0; n < 2; ++n)
#pragma unroll
        for (int kk = 0; kk < 2; ++kk)
          acc[m][n+2] = MFMA_BF16(aE[m][kk], b23E[n][kk], acc[m][n+2]);
    __builtin_amdgcn_s_setprio(0);
    asm volatile("s_waitcnt lgkmcnt(0)" ::: "memory");
    __builtin_amdgcn_sched_barrier(0);
    __builtin_amdgcn_s_barrier();
    // ---- tile to (buf1) ph0 ----
    if (to + 2 < NT) { GLL16(gA0 + 64, PDSTA(1,0)); GLL16(gA1 + 64, PDSTA(1,1));
                       GLL16(gA2 + 64, PDSTA(1,2)); GLL16(gA3 + 64, PDSTA(1,3)); }
#pragma unroll
    for (int n = 0; n < 2; ++n) { b23O[n][0] = rdB(1,n+2,0); b23O[n][1] = rdB(1,n+2,1); }
    __builtin_amdgcn_s_barrier();
    __builtin_amdgcn_s_setprio(1);
#pragma unroll
    for (int m = 0; m < 4; ++m)
#pragma unroll
      for (int n = 0; n < 2; ++n)
#pragma unroll
        for (int kk = 0; kk < 2; ++kk)
          acc[m][n] = MFMA_BF16(aO[m][kk], b01O[n][kk], acc[m][n]);
    __builtin_amdgcn_s_setprio(0);
    asm volatile("s_waitcnt lgkmcnt(0)" ::: "memory");
    __builtin_amdgcn_sched_barrier(0);
    __builtin_amdgcn_s_barrier();
    // ---- tile to ph1 ----
    if (to + 2 < NT) {
      GLL16(gB0 + 64, PDSTB(1,0)); GLL16(gB1 + 64, PDSTB(1,1));
      GLL16(gB2 + 64, PDSTB(1,2)); GLL16(gB3 + 64, PDSTB(1,3));
      asm volatile("s_waitcnt vmcnt(8)" ::: "memory");
    } else if (to + 1 < NT) {
      asm volatile("s_waitcnt vmcnt(0)" ::: "memory");
    }
    __builtin_amdgcn_sched_barrier(0);
    __builtin_amdgcn_s_barrier();
    if (to + 1 < NT) {
#pragma unroll
      for (int m = 0; m < 4; ++m) { aE[m][0] = rdA(0,m,0); aE[m][1] = rdA(0,m,1); }
#pragma unroll
      for (int n = 0; n < 2; ++n) { b01E[n][0] = rdB(0,n,0); b01E[n][1] = rdB(0,n,1); }
    }
    __builtin_amdgcn_s_setprio(1);
#pragma unroll
    for (int m = 0; m < 4; ++m)
#pragma unroll
      for (int n = 0; n < 2; ++n)
#pragma unroll
        for (int kk = 0; kk < 2; ++kk)
          acc[m][n+2] = MFMA_BF16(aO[m][kk], b23O[n][kk], acc[m][n+2]);
    __builtin_amdgcn_s_setprio(0);
    asm volatile("s_waitcnt lgkmcnt(0)" ::: "memory");
    __builtin_amdgcn_sched_barrier(0);
    __builtin_amdgcn_s_barrier();
    gA0 += 128; gA1 += 128; gA2 += 128; gA3 += 128;
    gB0 += 128; gB1 += 128; gB2 += 128; gB3 += 128;
  }
#undef PDSTA
#undef PDSTB

  const int row0 = m0 + wr * 64 + l4 * 4;
  const int col0 = n0 + wc * 64 + l15;
  if (MODE == 0) {
#pragma unroll
    for (int m = 0; m < 4; ++m)
#pragma unroll
      for (int n = 0; n < 4; ++n)
#pragma unroll
        for (int j = 0; j < 4; ++j)
          Cbf[(size_t)(row0 + m * 16 + j) * 4096 + col0 + n * 16] =
              f2b(acc[m][n][j] * scale);
  } else {
    float* Co = (float*)C;
    if (MODE == 2 && accum) {
#pragma unroll
      for (int m = 0; m < 4; ++m)
#pragma unroll
        for (int n = 0; n < 4; ++n)
#pragma unroll
          for (int j = 0; j < 4; ++j)
            Co[(size_t)(row0 + m * 16 + j) * 2048 + col0 + n * 16] += acc[m][n][j];
    } else {
#pragma unroll
      for (int m = 0; m < 4; ++m)
#pragma unroll
        for (int n = 0; n < 4; ++n)
#pragma unroll
          for (int j = 0; j < 4; ++j)
            Co[(size_t)(row0 + m * 16 + j) * 2048 + col0 + n * 16] = acc[m][n][j];
    }
  }
}

// In-place causal row softmax over bf16 [4096][4096]; causal-trimmed:
// row i touches only cols < L = (floor(i/128)+1)*128. Cols in (i, L) get
// zeros (read by K-clamped PV); cols >= L are never read downstream.
__global__ __launch_bounds__(256)
void softmax_causal(u16* __restrict__ S) {
  const int i = blockIdx.x;
  const int t = threadIdx.x;
  u16* row = S + (size_t)i * 4096;
  const int L = ((i >> 7) + 1) << 7;
  const bool act = (t * 16) < L;

  u16x8 r0 = {}, r1 = {};
  if (act) {
    r0 = *(const u16x8*)(row + t * 16);
    r1 = *(const u16x8*)(row + t * 16 + 8);
  }

  float v[16];
  float mx = -__builtin_inff();
#pragma unroll
  for (int c = 0; c < 16; ++c) {
    int j = t * 16 + c;
    float x = b2f(c < 8 ? r0[c] : r1[c - 8]);
    v[c] = (j <= i) ? x : -__builtin_inff();
    mx = fmaxf(mx, v[c]);
  }
#pragma unroll
  for (int off = 32; off >= 1; off >>= 1) mx = fmaxf(mx, __shfl_xor(mx, off));
  __shared__ float red[8];
  if ((t & 63) == 0) red[t >> 6] = mx;
  __syncthreads();
  mx = fmaxf(fmaxf(red[0], red[1]), fmaxf(red[2], red[3]));

  float s = 0.f;
#pragma unroll
  for (int c = 0; c < 16; ++c) {
    float e = exp2f((v[c] - mx) * 1.4426950408889634f);
    v[c] = e;
    s += e;
  }
#pragma unroll
  for (int off = 32; off >= 1; off >>= 1) s += __shfl_xor(s, off);
  if ((t & 63) == 0) red[4 + (t >> 6)] = s;
  __syncthreads();
  s = red[4] + red[5] + red[6] + red[7];
  float inv = 1.0f / s;

  if (act) {
    u16x8 o0, o1;
#pragma unroll
    for (int c = 0; c < 8; ++c) {
      o0[c] = f2b(v[c] * inv);
      o1[c] = f2b(v[c + 8] * inv);
    }
    *(u16x8*)(row + t * 16) = o0;
    *(u16x8*)(row + t * 16 + 8) = o1;
  }
}

extern "C" void kernel_launch(void* const* d_in, const int* in_sizes, int n_in,
                              void* d_out, int out_size, void* d_ws, size_t ws_size,
                              hipStream_t stream) {
  const float* x  = (const float*)d_in[0];
  const float* wq = (const float*)d_in[1];
  const float* wk = (const float*)d_in[2];
  const float* wv = (const float*)d_in[3];

  // workspace layout (bf16 elements); x|wq|wk|wv contiguous for fused cast
  u16* x_bf  = (u16*)d_ws;
  u16* wq_bf = x_bf  + (size_t)4096 * 2048;
  u16* wv_bf = wq_bf + (size_t)2 * 2048 * 2048;  // third weight slab
  u16* K_bf  = wq_bf + (size_t)3 * 2048 * 2048;
  u16* VT_bf = K_bf  + (size_t)4096 * 2048;
  u16* S_bf  = VT_bf + (size_t)2048 * 4096;
  u16* Q_bf  = (u16*)d_out;  // Q parked in d_out; dead before PV overwrites

  const float alpha = 0.022097086912079612f;  // 1/sqrt(2048)

  cast_all<<<dim3(10240), 256, 0, stream>>>(x, wq, wk, wv, x_bf);

  // [Q|K] = x . Wqk^T : 256x256 tiles, grid 16x16 = 256 = exactly 1 block/CU
  gemm_qk256<<<dim3(16, 16), 512, 131072, stream>>>(x_bf, wq_bf, Q_bf, K_bf);
  // Merged: S = alpha * Q . K^T (528 causal tiles) + VT = wv . x^T (512 tiles)
  pipe128<0><<<dim3(1040), 256, 65536, stream>>>(
      Q_bf, K_bf, S_bf, alpha, wv_bf, x_bf, VT_bf);
  // row softmax with causal mask, in place (causal-trimmed traffic)
  softmax_causal<<<dim3(4096), 256, 0, stream>>>(S_bf);
  // PVa: bm 16..31, K in [0,2048) — 256 uniform blocks, pure write
  pipe128<1><<<dim3(256), 256, 65536, stream>>>(
      S_bf, VT_bf, d_out, 1.0f, nullptr, nullptr, nullptr);
  // PVb: K-tails (accumulate) + bm<16 full-K (write), heavy-first, 512 blocks
  pipe128<2><<<dim3(512), 256, 65536, stream>>>(
      S_bf, VT_bf, d_out, 1.0f, nullptr, nullptr, nullptr);
}